// Round 8
// baseline (308.300 us; speedup 1.0000x reference)
//
#include <hip/hip_runtime.h>
#include <hip/hip_fp16.h>

#define TOKEN_DIM 16
#define RANGES 5
#define MAX_RS 20000   // +1 trash slot -> 80,004 B LDS -> still 2 blocks/CU
#define MAX_C  102     // grid1 = C*RANGES = 510 ~= 2 blocks x 256 CUs

// Phase 1: block (chunk c, range r) scans edge chunk c.
// Branchless inner loop: gather x[col] UNCONDITIONALLY (always valid) as an
// 8-wide independent load clause, then route each ds_add to either the real
// slot or a trash slot (index RS) via cndmask. No exec-mask regions, no
// serial gather->atomic chains.
__global__ __launch_bounds__(1024, 8)
void nit_phase1(const int* __restrict__ row, const int* __restrict__ col,
                const float* __restrict__ x,
                unsigned short* __restrict__ partial,   // [C][N] f16 bits
                int N, long long E, int chunkE, int RS) {
    __shared__ float acc[MAX_RS + 1];
    const int c = blockIdx.x / RANGES;
    const int r = blockIdx.x % RANGES;
    const int base = r * RS;
    int cnt = N - base; if (cnt > RS) cnt = RS; if (cnt < 0) cnt = 0;
    const int t = threadIdx.x, nt = blockDim.x;

    for (int j = t; j <= MAX_RS; j += nt) acc[j] = 0.0f;
    __syncthreads();

    long long i0 = (long long)c * chunkE;
    long long i1 = i0 + chunkE; if (i1 > E) i1 = E;
    long long len = (i1 > i0) ? (i1 - i0) : 0;
    long long ngrp = len >> 3;            // 8 edges/group (i0 is 8-aligned)

    for (long long g = t; g < ngrp; g += nt) {
        const int* rp = row + i0 + (g << 3);
        const int* cp = col + i0 + (g << 3);
        int4 r0 = *reinterpret_cast<const int4*>(rp);
        int4 r1 = *reinterpret_cast<const int4*>(rp + 4);
        int4 c0 = *reinterpret_cast<const int4*>(cp);
        int4 c1 = *reinterpret_cast<const int4*>(cp + 4);
        // unconditional gather clause: 8 independent L2 loads in flight
        float x0 = x[c0.x], x1 = x[c0.y], x2 = x[c0.z], x3 = x[c0.w];
        float x4 = x[c1.x], x5 = x[c1.y], x6 = x[c1.z], x7 = x[c1.w];
        unsigned d; int a;
        d = (unsigned)(r0.x - base); a = d < (unsigned)cnt ? (int)d : MAX_RS; atomicAdd(&acc[a], x0);
        d = (unsigned)(r0.y - base); a = d < (unsigned)cnt ? (int)d : MAX_RS; atomicAdd(&acc[a], x1);
        d = (unsigned)(r0.z - base); a = d < (unsigned)cnt ? (int)d : MAX_RS; atomicAdd(&acc[a], x2);
        d = (unsigned)(r0.w - base); a = d < (unsigned)cnt ? (int)d : MAX_RS; atomicAdd(&acc[a], x3);
        d = (unsigned)(r1.x - base); a = d < (unsigned)cnt ? (int)d : MAX_RS; atomicAdd(&acc[a], x4);
        d = (unsigned)(r1.y - base); a = d < (unsigned)cnt ? (int)d : MAX_RS; atomicAdd(&acc[a], x5);
        d = (unsigned)(r1.z - base); a = d < (unsigned)cnt ? (int)d : MAX_RS; atomicAdd(&acc[a], x6);
        d = (unsigned)(r1.w - base); a = d < (unsigned)cnt ? (int)d : MAX_RS; atomicAdd(&acc[a], x7);
    }
    for (long long idx = i0 + (ngrp << 3) + t; idx < i1; idx += nt) {
        unsigned d = (unsigned)(row[idx] - base);
        int a = d < (unsigned)cnt ? (int)d : MAX_RS;
        atomicAdd(&acc[a], x[col[idx]]);
    }
    __syncthreads();

    unsigned short* dst = partial + (size_t)c * N + base;
    for (int j = t; j < cnt; j += nt)
        dst[j] = __half_as_ushort(__float2half_rn(acc[j]));   // plain store: keep in L2/L3
}

// Phase 2: 64-node tile per block; C-chunk reduction split across 4 groups
// (coalesced f16 streams, L2/L3-served), LDS-reduced, then 64 threads run
// the 2->16->16 MLP.
__global__ __launch_bounds__(256, 8)
void nit_phase2(const float* __restrict__ x,
                const unsigned short* __restrict__ partial,
                const float* __restrict__ w1, const float* __restrict__ b1,
                const float* __restrict__ w2, const float* __restrict__ b2,
                float* __restrict__ out, int N, int C) {
    __shared__ float sw1[TOKEN_DIM * 2];
    __shared__ float sb1[TOKEN_DIM];
    __shared__ float sw2[TOKEN_DIM * TOKEN_DIM];
    __shared__ float sb2[TOKEN_DIM];
    __shared__ float red[256];

    const int t = threadIdx.x;
    if (t < TOKEN_DIM * TOKEN_DIM) sw2[t] = w2[t];
    if (t < TOKEN_DIM * 2) sw1[t] = w1[t];
    if (t < TOKEN_DIM) { sb1[t] = b1[t]; sb2[t] = b2[t]; }

    const int n = t & 63;
    const int g = t >> 6;
    const int node0 = blockIdx.x * 64;
    const int node = node0 + n;

    float s = 0.0f;
    if (node < N) {
#pragma unroll 4
        for (int c = g; c < C; c += 4)
            s += __half2float(__ushort_as_half(partial[(size_t)c * N + node]));
    }
    red[t] = s;
    __syncthreads();

    if (t < 64) {
        const int nn = node0 + t;
        if (nn < N) {
            const float ssum = red[t] + red[64 + t] + red[128 + t] + red[192 + t];
            const float xv = x[nn];
            const float lv = xv * ssum;

            float h[TOKEN_DIM];
#pragma unroll
            for (int j = 0; j < TOKEN_DIM; ++j) {
                float v = fmaf(xv, sw1[2 * j], fmaf(lv, sw1[2 * j + 1], sb1[j]));
                h[j] = v > 0.0f ? v : 0.0f;
            }

            float o[TOKEN_DIM];
#pragma unroll
            for (int j = 0; j < TOKEN_DIM; ++j) {
                float v = sb2[j];
#pragma unroll
                for (int k = 0; k < TOKEN_DIM; ++k)
                    v = fmaf(h[k], sw2[j * TOKEN_DIM + k], v);
                o[j] = v > 0.0f ? v : 0.0f;
            }

            float4* op = reinterpret_cast<float4*>(out + (size_t)nn * TOKEN_DIM);
#pragma unroll
            for (int j = 0; j < 4; ++j)
                op[j] = make_float4(o[4 * j], o[4 * j + 1], o[4 * j + 2], o[4 * j + 3]);
        }
    }
}

extern "C" void kernel_launch(void* const* d_in, const int* in_sizes, int n_in,
                              void* d_out, int out_size, void* d_ws, size_t ws_size,
                              hipStream_t stream) {
    const float* x  = (const float*)d_in[0];
    const int*   ei = (const int*)d_in[1];   // [2, E] flat: rows then cols
    const float* w1 = (const float*)d_in[2];
    const float* b1 = (const float*)d_in[3];
    const float* w2 = (const float*)d_in[4];
    const float* b2 = (const float*)d_in[5];
    float* out = (float*)d_out;

    const int N = in_sizes[0];
    const long long E = in_sizes[1] / 2;
    const int* row = ei;
    const int* col = ei + E;

    long long maxC = (long long)(ws_size / ((size_t)N * sizeof(unsigned short)));
    int C = maxC < 1 ? 1 : (maxC > MAX_C ? MAX_C : (int)maxC);
    const int RS = (N + RANGES - 1) / RANGES;     // 20000 for N=100000
    long long ce = (E + C - 1) / C;
    int chunkE = (int)((ce + 7LL) & ~7LL);        // 8-aligned for int4 group loads

    unsigned short* partial = (unsigned short*)d_ws;

    nit_phase1<<<C * RANGES, 1024, 0, stream>>>(row, col, x, partial,
                                                N, E, chunkE, RS);

    int grid2 = (N + 63) / 64;
    nit_phase2<<<grid2, 256, 0, stream>>>(x, partial, w1, b1, w2, b2,
                                          out, N, C);
}